// Round 14
// baseline (2708.796 us; speedup 1.0000x reference)
//
#include <hip/hip_runtime.h>

#define H_DIM   2048
#define N_HALF  1024
#define B_SZ    128
#define T_STEPS 512
#define IN_DIM  64
#define ALPHA_F 0.05f
#define OMA_F   0.95f   // 1 - ALPHA

typedef __bf16 bf16x8 __attribute__((ext_vector_type(8)));
typedef float  f32x4  __attribute__((ext_vector_type(4)));
typedef unsigned int u32x4 __attribute__((ext_vector_type(4)));

// round-to-nearest-even f32 -> bf16 bits
__device__ __forceinline__ unsigned short f2bf(float f) {
    union { float f; unsigned int u; } v; v.f = f;
    unsigned int u = v.u;
    u += 0x7FFFu + ((u >> 16) & 1u);
    return (unsigned short)(u >> 16);
}

// ---------------------------------------------------------------------------
// Wf: weights in MFMA-fragment order:
//   Wf[(j>>6)*131072 + ((ks*4 + q4)*64 + (j&63))*8 + e] = bf16(W[k][j])
//   with ks = k>>5, q4 = (k>>3)&3, e = k&7.
// ---------------------------------------------------------------------------
__global__ void wf_kernel(const float* __restrict__ W, unsigned short* __restrict__ Wf) {
    __shared__ float tile[64][65];     // tile[kk][jj] = W[kb+kk][jb+jj]
    const int jb = blockIdx.x * 64;
    const int kb = blockIdx.y * 64;
    const int t  = threadIdx.y * 64 + threadIdx.x;   // 0..255
    const int tx = threadIdx.x, ty = threadIdx.y;
    #pragma unroll
    for (int r = ty; r < 64; r += 4)
        tile[r][tx] = W[(size_t)(kb + r) * H_DIM + jb + tx];
    __syncthreads();
    #pragma unroll
    for (int cc = 0; cc < 2; ++cc) {
        const int c  = t * 2 + cc;        // 0..511
        const int jj = c >> 3;            // 0..63
        const int kc = c & 7;             // 8-K group within tile
        const int j  = jb + jj;
        const int k0 = kb + kc * 8;
        unsigned short v[8];
        #pragma unroll
        for (int e = 0; e < 8; ++e)
            v[e] = f2bf(tile[kc * 8 + e][jj]);
        const int ks = k0 >> 5;
        const int q4 = (k0 >> 3) & 3;
        const size_t dst = (size_t)(j >> 6) * 131072 +
                           ((size_t)(ks * 4 + q4) * 64 + (j & 63)) * 8;
        *reinterpret_cast<u32x4*>(Wf + dst) = *reinterpret_cast<u32x4*>(v);
    }
}

// ---------------------------------------------------------------------------
__global__ void vel_kernel(const float* __restrict__ x, const float* __restrict__ w_in,
                           float* __restrict__ vel) {
    const int tb = blockIdx.x * blockDim.x + threadIdx.x;
    if (tb >= T_STEPS * B_SZ) return;
    const float* xp = x + (size_t)tb * IN_DIM;
    float s = 0.f;
    #pragma unroll
    for (int i = 0; i < IN_DIM; i += 4) {
        float4 xv = *reinterpret_cast<const float4*>(xp + i);
        float4 wv = *reinterpret_cast<const float4*>(w_in + i);
        s += xv.x * wv.x + xv.y * wv.y + xv.z * wv.z + xv.w * wv.w;
    }
    vel[tb] = s;
}

// ---------------------------------------------------------------------------
__global__ void hbf_init_kernel(const float* __restrict__ h0, unsigned short* __restrict__ hbf) {
    const int i = blockIdx.x * blockDim.x + threadIdx.x;
    hbf[i] = f2bf(h0[i]);
}

// ---------------------------------------------------------------------------
// Persistent kernel: 256 blocks (1/CU) x 512 threads (8 waves).
// Block tile 16 rows x 64 cols; 8 waves = 4 col-quarters x 2 K-halves.
// r13: B in registers (Breg[32], loaded once — W constant).
// r14: A loads CACHED again. Protocol (r5-proven): every in-loop global store
// bypasses L2 (sc0 sc1 / nt), so a buffer_inv sc1 acquire can never lose
// data; wave 0 polls ALL 32 producer flags wave-parallel, executes ONE
// buffer_inv, then __syncthreads orders it before all waves' cached loads.
// Locality heuristic (correctness-independent): rowg = bid&7 -> under
// round-robin dispatch a rowg's 32 blocks share one XCD, so the shared
// 1MB row-panel is pulled from L3 once per XCD per step and L2 serves
// the 32x redundancy. h handoff stores sc0+sc1; acts nt; h_prev in regs.
// ---------------------------------------------------------------------------
__global__ __launch_bounds__(512, 1) void ring_coop_kernel(
        const unsigned short* __restrict__ Wf,
        unsigned short* __restrict__ hbf0,
        unsigned short* __restrict__ hbf1,
        const float* __restrict__ vel,
        const float* __restrict__ hidden0,
        float* __restrict__ acts,
        float* __restrict__ outT,
        unsigned* __restrict__ flags) {
    __shared__ __align__(16) unsigned char A_lds[65536];   // swizzled frag chunks
    __shared__ __align__(16) f32x4 pacc[256];              // [colq][lane]
    __shared__ __align__(16) float hbuf[16][64];           // epilogue transpose

    const int tid = threadIdx.x;
    const int bid = blockIdx.x;
    // Locality remap: same-XCD blocks (bid%8 equal) share rowg.
    const int rowg = bid & 7;          // 0..7  (16-row groups)
    const int colg = bid >> 3;         // 0..31 (64-col groups)
    const int colbase = colg * 64;
    const int rowbase = rowg * 16;

    const int lane = tid & 63, w = tid >> 6;   // 8 waves
    const int colq = w & 3, khalf = w >> 2;
    const int r16 = lane & 15, q4 = lane >> 4;
    const int j = colbase + colq * 16 + r16;
    const float gamma = (j < N_HALF) ? -1.0f : 1.0f;

    // staging lane identity: rows srow / srow+8, K-subchunk kcl (8 K each)
    const int srow = lane >> 3;      // 0..7
    const int kcl  = lane & 7;       // 0..7

    unsigned* rflags = flags + rowg * 128;    // flag for cg at rflags[cg*4]

    // ---- one-time: B fragments into registers (W constant across steps) ----
    const unsigned short* bgbase = Wf + (size_t)colg * 131072
                                   + (size_t)(khalf * 128 + q4) * 512
                                   + (size_t)(colq * 16 + r16) * 8;
    bf16x8 Breg[32];
    #pragma unroll
    for (int s = 0; s < 32; ++s)
        Breg[s] = *reinterpret_cast<const bf16x8*>(bgbase + (size_t)s * 2048);

    // h_prev registers (khalf==0 waves): rows rowbase+q4*4+i, col j
    f32x4 hreg = {0.f, 0.f, 0.f, 0.f};
    if (khalf == 0) {
        #pragma unroll
        for (int i = 0; i < 4; ++i)
            hreg[i] = hidden0[(size_t)(rowbase + q4 * 4 + i) * H_DIM + j];
    }

    const int xe = r16 ^ q4;     // read swizzle, even s
    const int xo = xe ^ 4;       // read swizzle, odd  s

    for (int t = 0; t < T_STEPS; ++t) {
        const unsigned short* hin  = (t & 1) ? hbf1 : hbf0;
        unsigned short*       hout = (t & 1) ? hbf0 : hbf1;
        const float* vel_t = vel + (size_t)t * B_SZ;
        float* acts_t = acts + (size_t)t * B_SZ * H_DIM;

        // ---- acquire: wave 0 polls ALL 32 producer flags in parallel ----
        if (w == 0) {
            for (;;) {
                int ok = 1;
                if (lane < 32) {
                    unsigned v = __hip_atomic_load(rflags + lane * 4,
                                     __ATOMIC_RELAXED, __HIP_MEMORY_SCOPE_AGENT);
                    ok = (v >= (unsigned)t);
                }
                if (__all(ok)) break;
                __builtin_amdgcn_s_sleep(1);
            }
            // drop stale L1/L2 lines; nothing dirty can be lost (all in-loop
            // stores bypass L2). One inv per block per step.
            asm volatile("buffer_inv sc1\n\ts_waitcnt vmcnt(0)" ::: "memory");
        }
        __syncthreads();   // inv ordered before every wave's cached loads

        // ---- stage A panel: 4 chunks/wave, CACHED 16B loads ----
        {
            #pragma unroll
            for (int i = 0; i < 4; ++i) {
                const int cg = w * 4 + i;
                const unsigned short* ap =
                    hin + (size_t)(rowbase + srow) * H_DIM + cg * 64 + kcl * 8;
                u32x4 lo = *reinterpret_cast<const u32x4*>(ap);
                u32x4 hi = *reinterpret_cast<const u32x4*>(ap + 8 * H_DIM);
                *reinterpret_cast<u32x4*>(A_lds +
                    (size_t)((cg * 8 + kcl) * 16 + (srow ^ kcl)) * 16) = lo;
                *reinterpret_cast<u32x4*>(A_lds +
                    (size_t)((cg * 8 + kcl) * 16 + ((srow + 8) ^ kcl)) * 16) = hi;
            }
        }
        __syncthreads();

        // ---- GEMM: 32 MFMAs/wave, A from swizzled LDS, B from REGISTERS ----
        const unsigned char* Abase = A_lds + (size_t)(khalf * 2048 + q4 * 16) * 16;
        f32x4 acc0 = {0.f,0.f,0.f,0.f}, acc1 = {0.f,0.f,0.f,0.f};
        f32x4 acc2 = {0.f,0.f,0.f,0.f}, acc3 = {0.f,0.f,0.f,0.f};
        #pragma unroll
        for (int s = 0; s < 32; s += 4) {
            bf16x8 a0 = *reinterpret_cast<const bf16x8*>(Abase +
                (size_t)((s + 0) * 64 + xe) * 16);
            bf16x8 a1 = *reinterpret_cast<const bf16x8*>(Abase +
                (size_t)((s + 1) * 64 + xo) * 16);
            bf16x8 a2 = *reinterpret_cast<const bf16x8*>(Abase +
                (size_t)((s + 2) * 64 + xe) * 16);
            bf16x8 a3 = *reinterpret_cast<const bf16x8*>(Abase +
                (size_t)((s + 3) * 64 + xo) * 16);
            acc0 = __builtin_amdgcn_mfma_f32_16x16x32_bf16(a0, Breg[s + 0], acc0, 0, 0, 0);
            acc1 = __builtin_amdgcn_mfma_f32_16x16x32_bf16(a1, Breg[s + 1], acc1, 0, 0, 0);
            acc2 = __builtin_amdgcn_mfma_f32_16x16x32_bf16(a2, Breg[s + 2], acc2, 0, 0, 0);
            acc3 = __builtin_amdgcn_mfma_f32_16x16x32_bf16(a3, Breg[s + 3], acc3, 0, 0, 0);
        }
        f32x4 psum = (acc0 + acc1) + (acc2 + acc3);

        // ---- K-pair reduce + epilogue into hbuf ----
        if (khalf == 1) pacc[colq * 64 + lane] = psum;
        __syncthreads();
        if (khalf == 0) {
            const f32x4 h2h = psum + pacc[colq * 64 + lane];
            const f32x4 vel4 = *reinterpret_cast<const f32x4*>(vel_t + rowbase + q4 * 4);
            #pragma unroll
            for (int i = 0; i < 4; ++i) {
                const float pre = fmaf(vel4[i], gamma, 1.0f) + h2h[i];
                const float hn = OMA_F * hreg[i] + ALPHA_F * fmaxf(pre, 0.0f);
                hreg[i] = hn;
                hbuf[q4 * 4 + i][colq * 16 + r16] = hn;
            }
        }
        __syncthreads();

        // ---- wide bypass stores from hbuf (split across waves) ----
        if (tid < 256) {                 // acts f32: 256 x 16B, nt (no drain req)
            const int row3 = tid >> 4, c4 = (tid & 15) * 4;
            f32x4 va = *reinterpret_cast<const f32x4*>(&hbuf[row3][c4]);
            float* dst = acts_t + (size_t)(rowbase + row3) * H_DIM + colbase + c4;
            asm volatile("global_store_dwordx4 %0, %1, off sc0 sc1 nt"
                         :: "v"(dst), "v"(va) : "memory");
        } else if (tid < 384) {          // h bf16: 128 x 16B, sc0 sc1 + drain
            const int t2 = tid - 256;
            const int row2 = t2 >> 3, c8 = (t2 & 7) * 8;
            unsigned pk[4];
            #pragma unroll
            for (int e = 0; e < 4; ++e)
                pk[e] = (unsigned)f2bf(hbuf[row2][c8 + 2 * e]) |
                        ((unsigned)f2bf(hbuf[row2][c8 + 2 * e + 1]) << 16);
            u32x4 hv = {pk[0], pk[1], pk[2], pk[3]};
            unsigned short* dst = hout + (size_t)(rowbase + row2) * H_DIM + colbase + c8;
            asm volatile("global_store_dwordx4 %0, %1, off sc0 sc1"
                         :: "v"(dst), "v"(hv) : "memory");
            asm volatile("s_waitcnt vmcnt(0)" ::: "memory");
        } else if (t == T_STEPS - 1) {   // hT tail: 128 threads x 2 stores, plain
            #pragma unroll
            for (int e = 0; e < 2; ++e) {
                const int idx = (tid - 384) * 2 + e;
                const int row3 = idx >> 4, c4 = (idx & 15) * 4;
                f32x4 va = *reinterpret_cast<const f32x4*>(&hbuf[row3][c4]);
                *reinterpret_cast<f32x4*>(outT +
                    (size_t)(rowbase + row3) * H_DIM + colbase + c4) = va;
            }
        }
        __syncthreads();                 // h stores of all producers drained
        if (tid == 0 && t < T_STEPS - 1)
            __hip_atomic_store(rflags + colg * 4, (unsigned)(t + 1),
                               __ATOMIC_RELAXED, __HIP_MEMORY_SCOPE_AGENT);
    }
}

// ---------------------------------------------------------------------------
// Fallback per-step kernel (Wf layout) if cooperative launch fails.
// ---------------------------------------------------------------------------
__global__ __launch_bounds__(256) void step_kernel(
        const unsigned short* __restrict__ Wf,
        const unsigned short* __restrict__ hbf_in,
        unsigned short* __restrict__ hbf_out,
        const float* __restrict__ vel_t,
        const float* __restrict__ hprev,
        float* __restrict__ acts_t,
        float* __restrict__ outT) {
    const int lane = threadIdx.x & 63;
    const int w    = threadIdx.x >> 6;
    const int bid  = blockIdx.x;
    const int mg   = bid >> 7;
    const int n    = bid & 127;
    const int base_b = mg * 64 + w * 16;
    const int base_j = n * 16;
    const int r16  = lane & 15;
    const int q4   = lane >> 4;

    const int j = base_j + r16;
    const bf16x8* Ap = reinterpret_cast<const bf16x8*>(
        hbf_in + (size_t)(base_b + r16) * H_DIM + q4 * 8);
    const unsigned short* wslot = Wf + (size_t)(j >> 6) * 131072 + (size_t)(j & 63) * 8;

    f32x4 acc0 = {0.f, 0.f, 0.f, 0.f};
    f32x4 acc1 = {0.f, 0.f, 0.f, 0.f};
    #pragma unroll 8
    for (int kk = 0; kk < 32; ++kk) {
        bf16x8 a0 = Ap[kk * 4];
        bf16x8 a1 = Ap[kk * 4 + 128];
        bf16x8 b0 = *reinterpret_cast<const bf16x8*>(wslot + (size_t)(kk * 4 + q4) * 512);
        bf16x8 b1 = *reinterpret_cast<const bf16x8*>(wslot + (size_t)((kk + 32) * 4 + q4) * 512);
        acc0 = __builtin_amdgcn_mfma_f32_16x16x32_bf16(a0, b0, acc0, 0, 0, 0);
        acc1 = __builtin_amdgcn_mfma_f32_16x16x32_bf16(a1, b1, acc1, 0, 0, 0);
    }
    f32x4 h2h = acc0 + acc1;

    const float gamma = (j < N_HALF) ? -1.0f : 1.0f;
    const int brow0 = base_b + q4 * 4;
    #pragma unroll
    for (int i = 0; i < 4; ++i) {
        const int b = brow0 + i;
        const float v  = vel_t[b];
        const float hp = hprev[(size_t)b * H_DIM + j];
        const float pre = fmaf(v, gamma, 1.0f) + h2h[i];
        const float hn = OMA_F * hp + ALPHA_F * fmaxf(pre, 0.0f);
        acts_t[(size_t)b * H_DIM + j] = hn;
        hbf_out[(size_t)b * H_DIM + j] = f2bf(hn);
        if (outT) outT[(size_t)b * H_DIM + j] = hn;
    }
}

// ---------------------------------------------------------------------------
extern "C" void kernel_launch(void* const* d_in, const int* in_sizes, int n_in,
                              void* d_out, int out_size, void* d_ws, size_t ws_size,
                              hipStream_t stream) {
    const float* x       = (const float*)d_in[0];  // [T,B,IN]
    const float* hidden0 = (const float*)d_in[1];  // [B,H]
    const float* w_attr  = (const float*)d_in[2];  // [H,H]
    const float* w_in    = (const float*)d_in[3];  // [1,IN]

    float* acts = (float*)d_out;                               // [T,B,H]
    float* outT = acts + (size_t)T_STEPS * B_SZ * H_DIM;       // [B,H]

    unsigned char* ws = (unsigned char*)d_ws;
    unsigned short* Wf   = (unsigned short*)ws;                             // 8 MB
    unsigned short* hbf0 = (unsigned short*)(ws + ((size_t)8 << 20));       // 512 KB
    unsigned short* hbf1 = hbf0 + (size_t)B_SZ * H_DIM;                     // 512 KB
    float* vel = (float*)(ws + ((size_t)8 << 20) + (size_t)2 * B_SZ * H_DIM * 2); // 256 KB
    unsigned* flags = (unsigned*)(ws + ((size_t)8 << 20) + ((size_t)1 << 20) + (256 << 10)); // 4 KB

    hipMemsetAsync(flags, 0, 4096, stream);
    wf_kernel<<<dim3(32, 32), dim3(64, 4), 0, stream>>>(w_attr, Wf);
    vel_kernel<<<(T_STEPS * B_SZ + 255) / 256, 256, 0, stream>>>(x, w_in, vel);
    hbf_init_kernel<<<(B_SZ * H_DIM + 255) / 256, 256, 0, stream>>>(hidden0, hbf0);

    void* args[] = {(void*)&Wf, (void*)&hbf0, (void*)&hbf1, (void*)&vel,
                    (void*)&hidden0, (void*)&acts, (void*)&outT, (void*)&flags};
    hipError_t rc = hipLaunchCooperativeKernel(
        reinterpret_cast<void*>(ring_coop_kernel),
        dim3(256), dim3(512), args, 0, stream);

    if (rc != hipSuccess) {
        // fallback: per-step launches
        for (int t = 0; t < T_STEPS; ++t) {
            const unsigned short* hin = (t & 1) ? hbf1 : hbf0;
            unsigned short* hout      = (t & 1) ? hbf0 : hbf1;
            const float* hprev = (t == 0) ? hidden0 : acts + (size_t)(t - 1) * B_SZ * H_DIM;
            step_kernel<<<256, 256, 0, stream>>>(
                Wf, hin, hout, vel + (size_t)t * B_SZ, hprev,
                acts + (size_t)t * B_SZ * H_DIM,
                (t == T_STEPS - 1) ? outT : nullptr);
        }
    }
}

// Round 15
// 1959.894 us; speedup vs baseline: 1.3821x; 1.3821x over previous
//
#include <hip/hip_runtime.h>

#define H_DIM   2048
#define N_HALF  1024
#define B_SZ    128
#define T_STEPS 512
#define IN_DIM  64
#define ALPHA_F 0.05f
#define OMA_F   0.95f   // 1 - ALPHA

typedef __bf16 bf16x8 __attribute__((ext_vector_type(8)));
typedef float  f32x4  __attribute__((ext_vector_type(4)));
typedef unsigned int u32x4 __attribute__((ext_vector_type(4)));

// round-to-nearest-even f32 -> bf16 bits
__device__ __forceinline__ unsigned short f2bf(float f) {
    union { float f; unsigned int u; } v; v.f = f;
    unsigned int u = v.u;
    u += 0x7FFFu + ((u >> 16) & 1u);
    return (unsigned short)(u >> 16);
}

// ---------------------------------------------------------------------------
// Wf: weights in MFMA-fragment order:
//   Wf[(j>>6)*131072 + ((ks*4 + q4)*64 + (j&63))*8 + e] = bf16(W[k][j])
//   with ks = k>>5, q4 = (k>>3)&3, e = k&7.
// ---------------------------------------------------------------------------
__global__ void wf_kernel(const float* __restrict__ W, unsigned short* __restrict__ Wf) {
    __shared__ float tile[64][65];     // tile[kk][jj] = W[kb+kk][jb+jj]
    const int jb = blockIdx.x * 64;
    const int kb = blockIdx.y * 64;
    const int t  = threadIdx.y * 64 + threadIdx.x;   // 0..255
    const int tx = threadIdx.x, ty = threadIdx.y;
    #pragma unroll
    for (int r = ty; r < 64; r += 4)
        tile[r][tx] = W[(size_t)(kb + r) * H_DIM + jb + tx];
    __syncthreads();
    #pragma unroll
    for (int cc = 0; cc < 2; ++cc) {
        const int c  = t * 2 + cc;        // 0..511
        const int jj = c >> 3;            // 0..63
        const int kc = c & 7;             // 8-K group within tile
        const int j  = jb + jj;
        const int k0 = kb + kc * 8;
        unsigned short v[8];
        #pragma unroll
        for (int e = 0; e < 8; ++e)
            v[e] = f2bf(tile[kc * 8 + e][jj]);
        const int ks = k0 >> 5;
        const int q4 = (k0 >> 3) & 3;
        const size_t dst = (size_t)(j >> 6) * 131072 +
                           ((size_t)(ks * 4 + q4) * 64 + (j & 63)) * 8;
        *reinterpret_cast<u32x4*>(Wf + dst) = *reinterpret_cast<u32x4*>(v);
    }
}

// ---------------------------------------------------------------------------
__global__ void vel_kernel(const float* __restrict__ x, const float* __restrict__ w_in,
                           float* __restrict__ vel) {
    const int tb = blockIdx.x * blockDim.x + threadIdx.x;
    if (tb >= T_STEPS * B_SZ) return;
    const float* xp = x + (size_t)tb * IN_DIM;
    float s = 0.f;
    #pragma unroll
    for (int i = 0; i < IN_DIM; i += 4) {
        float4 xv = *reinterpret_cast<const float4*>(xp + i);
        float4 wv = *reinterpret_cast<const float4*>(w_in + i);
        s += xv.x * wv.x + xv.y * wv.y + xv.z * wv.z + xv.w * wv.w;
    }
    vel[tb] = s;
}

// ---------------------------------------------------------------------------
__global__ void hbf_init_kernel(const float* __restrict__ h0, unsigned short* __restrict__ hbf) {
    const int i = blockIdx.x * blockDim.x + threadIdx.x;
    hbf[i] = f2bf(h0[i]);
}

// ---------------------------------------------------------------------------
// Persistent kernel: 256 blocks (1/CU) x 512 threads (8 waves).
// Block tile 16 rows x 64 cols; 8 waves = 4 col-quarters x 2 K-halves.
// r13 protocol (best: 2180us): B in registers (Breg[32], W constant);
// all mutable traffic bypasses caches (h handoff sc0+sc1 both sides, acts
// nt); immutable (Wf, vel) cached; ZERO cache-maintenance ops (r14's
// buffer_inv regressed). h_prev in registers.
// r15: staging restructured — ONE wave-parallel poll of the wave's 4
// producer flags (4 lanes + __all, was 4 serial poll RTTs), then 8x16B
// sc0 sc1 loads all in flight (was 16x8B in a depth-2 chain).
// LDS chunk swizzle row^kcl (conflict-free staging writes + frag reads).
// ---------------------------------------------------------------------------
__global__ __launch_bounds__(512, 1) void ring_coop_kernel(
        const unsigned short* __restrict__ Wf,
        unsigned short* __restrict__ hbf0,
        unsigned short* __restrict__ hbf1,
        const float* __restrict__ vel,
        const float* __restrict__ hidden0,
        float* __restrict__ acts,
        float* __restrict__ outT,
        unsigned* __restrict__ flags) {
    __shared__ __align__(16) unsigned char A_lds[65536];   // swizzled frag chunks
    __shared__ __align__(16) f32x4 pacc[256];              // [colq][lane]
    __shared__ __align__(16) float hbuf[16][64];           // epilogue transpose

    const int tid = threadIdx.x;
    const int bid = blockIdx.x;
    // XCD swizzle (bid%8 = XCD): XCD x owns colgs {4x..4x+3} for ALL rowgs.
    const int colg = (bid & 7) * 4 + ((bid >> 3) & 3);   // 0..31 (64-col groups)
    const int rowg = bid >> 5;                            // 0..7  (16-row groups)
    const int colbase = colg * 64;
    const int rowbase = rowg * 16;

    const int lane = tid & 63, w = tid >> 6;   // 8 waves
    const int colq = w & 3, khalf = w >> 2;
    const int r16 = lane & 15, q4 = lane >> 4;
    const int j = colbase + colq * 16 + r16;
    const float gamma = (j < N_HALF) ? -1.0f : 1.0f;

    // staging lane identity: rows srow / srow+8, K-subchunk kcl (8 K each)
    const int srow = lane >> 3;      // 0..7
    const int kcl  = lane & 7;       // 0..7

    unsigned* rflags = flags + rowg * 128;    // flag for cg at rflags[cg*4]

    // ---- one-time: B fragments into registers (W constant across steps) ----
    const unsigned short* bgbase = Wf + (size_t)colg * 131072
                                   + (size_t)(khalf * 128 + q4) * 512
                                   + (size_t)(colq * 16 + r16) * 8;
    bf16x8 Breg[32];
    #pragma unroll
    for (int s = 0; s < 32; ++s)
        Breg[s] = *reinterpret_cast<const bf16x8*>(bgbase + (size_t)s * 2048);

    // h_prev registers (khalf==0 waves): rows rowbase+q4*4+i, col j
    f32x4 hreg = {0.f, 0.f, 0.f, 0.f};
    if (khalf == 0) {
        #pragma unroll
        for (int i = 0; i < 4; ++i)
            hreg[i] = hidden0[(size_t)(rowbase + q4 * 4 + i) * H_DIM + j];
    }

    const int xe = r16 ^ q4;     // read swizzle, even s
    const int xo = xe ^ 4;       // read swizzle, odd  s

    // this wave's 4 staged chunks: cg0 + {0,8,16,24} (mod 32)
    const int cg0 = (colg + 1 + w) & 31;
    const int cgA = cg0, cgB = (cg0 + 8) & 31, cgC = (cg0 + 16) & 31, cgD = (cg0 + 24) & 31;
    // flag index this lane polls (lanes 0..3)
    const int pollcg = (cg0 + 8 * (lane & 3)) & 31;

    for (int t = 0; t < T_STEPS; ++t) {
        const unsigned short* hin  = (t & 1) ? hbf1 : hbf0;
        unsigned short*       hout = (t & 1) ? hbf0 : hbf1;
        const float* vel_t = vel + (size_t)t * B_SZ;
        float* acts_t = acts + (size_t)t * B_SZ * H_DIM;

        // ---- ONE wave-parallel poll of this wave's 4 producer flags ----
        for (;;) {
            int ok = 1;
            if (lane < 4) {
                unsigned v = __hip_atomic_load(rflags + pollcg * 4,
                                 __ATOMIC_RELAXED, __HIP_MEMORY_SCOPE_AGENT);
                ok = (v >= (unsigned)t);
            }
            if (__all(ok)) break;
            __builtin_amdgcn_s_sleep(1);
        }
        asm volatile("" ::: "memory");   // loads below can't hoist above poll

        // ---- stage 4 chunks: 8 x 16B sc0 sc1 loads, all in flight ----
        {
            const unsigned short* base = hin + (size_t)(rowbase + srow) * H_DIM + kcl * 8;
            u32x4 a0, a1, b0, b1, c0, c1, d0, d1;
            const unsigned short* pA = base + cgA * 64;
            const unsigned short* pB = base + cgB * 64;
            const unsigned short* pC = base + cgC * 64;
            const unsigned short* pD = base + cgD * 64;
            asm volatile("global_load_dwordx4 %0, %1, off sc0 sc1" : "=v"(a0) : "v"(pA));
            asm volatile("global_load_dwordx4 %0, %1, off sc0 sc1" : "=v"(a1) : "v"(pA + 8 * H_DIM));
            asm volatile("global_load_dwordx4 %0, %1, off sc0 sc1" : "=v"(b0) : "v"(pB));
            asm volatile("global_load_dwordx4 %0, %1, off sc0 sc1" : "=v"(b1) : "v"(pB + 8 * H_DIM));
            asm volatile("global_load_dwordx4 %0, %1, off sc0 sc1" : "=v"(c0) : "v"(pC));
            asm volatile("global_load_dwordx4 %0, %1, off sc0 sc1" : "=v"(c1) : "v"(pC + 8 * H_DIM));
            asm volatile("global_load_dwordx4 %0, %1, off sc0 sc1" : "=v"(d0) : "v"(pD));
            asm volatile("global_load_dwordx4 %0, %1, off sc0 sc1" : "=v"(d1) : "v"(pD + 8 * H_DIM));
            asm volatile("s_waitcnt vmcnt(0)" ::: "memory");
            __builtin_amdgcn_sched_barrier(0);
            const int lo_sw = srow ^ kcl, hi_sw = (srow + 8) ^ kcl;
            *reinterpret_cast<u32x4*>(A_lds + (size_t)((cgA * 8 + kcl) * 16 + lo_sw) * 16) = a0;
            *reinterpret_cast<u32x4*>(A_lds + (size_t)((cgA * 8 + kcl) * 16 + hi_sw) * 16) = a1;
            *reinterpret_cast<u32x4*>(A_lds + (size_t)((cgB * 8 + kcl) * 16 + lo_sw) * 16) = b0;
            *reinterpret_cast<u32x4*>(A_lds + (size_t)((cgB * 8 + kcl) * 16 + hi_sw) * 16) = b1;
            *reinterpret_cast<u32x4*>(A_lds + (size_t)((cgC * 8 + kcl) * 16 + lo_sw) * 16) = c0;
            *reinterpret_cast<u32x4*>(A_lds + (size_t)((cgC * 8 + kcl) * 16 + hi_sw) * 16) = c1;
            *reinterpret_cast<u32x4*>(A_lds + (size_t)((cgD * 8 + kcl) * 16 + lo_sw) * 16) = d0;
            *reinterpret_cast<u32x4*>(A_lds + (size_t)((cgD * 8 + kcl) * 16 + hi_sw) * 16) = d1;
        }
        __syncthreads();

        // ---- GEMM: 32 MFMAs/wave, A from swizzled LDS, B from REGISTERS ----
        const unsigned char* Abase = A_lds + (size_t)(khalf * 2048 + q4 * 16) * 16;
        f32x4 acc0 = {0.f,0.f,0.f,0.f}, acc1 = {0.f,0.f,0.f,0.f};
        f32x4 acc2 = {0.f,0.f,0.f,0.f}, acc3 = {0.f,0.f,0.f,0.f};
        #pragma unroll
        for (int s = 0; s < 32; s += 4) {
            bf16x8 a0 = *reinterpret_cast<const bf16x8*>(Abase +
                (size_t)((s + 0) * 64 + xe) * 16);
            bf16x8 a1 = *reinterpret_cast<const bf16x8*>(Abase +
                (size_t)((s + 1) * 64 + xo) * 16);
            bf16x8 a2 = *reinterpret_cast<const bf16x8*>(Abase +
                (size_t)((s + 2) * 64 + xe) * 16);
            bf16x8 a3 = *reinterpret_cast<const bf16x8*>(Abase +
                (size_t)((s + 3) * 64 + xo) * 16);
            acc0 = __builtin_amdgcn_mfma_f32_16x16x32_bf16(a0, Breg[s + 0], acc0, 0, 0, 0);
            acc1 = __builtin_amdgcn_mfma_f32_16x16x32_bf16(a1, Breg[s + 1], acc1, 0, 0, 0);
            acc2 = __builtin_amdgcn_mfma_f32_16x16x32_bf16(a2, Breg[s + 2], acc2, 0, 0, 0);
            acc3 = __builtin_amdgcn_mfma_f32_16x16x32_bf16(a3, Breg[s + 3], acc3, 0, 0, 0);
        }
        f32x4 psum = (acc0 + acc1) + (acc2 + acc3);

        // ---- K-pair reduce + epilogue into hbuf ----
        if (khalf == 1) pacc[colq * 64 + lane] = psum;
        __syncthreads();
        if (khalf == 0) {
            const f32x4 h2h = psum + pacc[colq * 64 + lane];
            const f32x4 vel4 = *reinterpret_cast<const f32x4*>(vel_t + rowbase + q4 * 4);
            #pragma unroll
            for (int i = 0; i < 4; ++i) {
                const float pre = fmaf(vel4[i], gamma, 1.0f) + h2h[i];
                const float hn = OMA_F * hreg[i] + ALPHA_F * fmaxf(pre, 0.0f);
                hreg[i] = hn;
                hbuf[q4 * 4 + i][colq * 16 + r16] = hn;
            }
        }
        __syncthreads();

        // ---- wide bypass stores from hbuf (split across waves) ----
        if (tid < 256) {                 // acts f32: 256 x 16B, nt (no drain req)
            const int row3 = tid >> 4, c4 = (tid & 15) * 4;
            f32x4 va = *reinterpret_cast<const f32x4*>(&hbuf[row3][c4]);
            float* dst = acts_t + (size_t)(rowbase + row3) * H_DIM + colbase + c4;
            asm volatile("global_store_dwordx4 %0, %1, off sc0 sc1 nt"
                         :: "v"(dst), "v"(va) : "memory");
        } else if (tid < 384) {          // h bf16: 128 x 16B, sc0 sc1 + drain
            const int t2 = tid - 256;
            const int row2 = t2 >> 3, c8 = (t2 & 7) * 8;
            unsigned pk[4];
            #pragma unroll
            for (int e = 0; e < 4; ++e)
                pk[e] = (unsigned)f2bf(hbuf[row2][c8 + 2 * e]) |
                        ((unsigned)f2bf(hbuf[row2][c8 + 2 * e + 1]) << 16);
            u32x4 hv = {pk[0], pk[1], pk[2], pk[3]};
            unsigned short* dst = hout + (size_t)(rowbase + row2) * H_DIM + colbase + c8;
            asm volatile("global_store_dwordx4 %0, %1, off sc0 sc1"
                         :: "v"(dst), "v"(hv) : "memory");
            asm volatile("s_waitcnt vmcnt(0)" ::: "memory");
        } else if (t == T_STEPS - 1) {   // hT tail: 128 threads x 2 stores, plain
            #pragma unroll
            for (int e = 0; e < 2; ++e) {
                const int idx = (tid - 384) * 2 + e;
                const int row3 = idx >> 4, c4 = (idx & 15) * 4;
                f32x4 va = *reinterpret_cast<const f32x4*>(&hbuf[row3][c4]);
                *reinterpret_cast<f32x4*>(outT +
                    (size_t)(rowbase + row3) * H_DIM + colbase + c4) = va;
            }
        }
        __syncthreads();                 // h stores of all producers drained
        if (tid == 0 && t < T_STEPS - 1)
            __hip_atomic_store(rflags + colg * 4, (unsigned)(t + 1),
                               __ATOMIC_RELAXED, __HIP_MEMORY_SCOPE_AGENT);
    }
}

// ---------------------------------------------------------------------------
// Fallback per-step kernel (Wf layout) if cooperative launch fails.
// ---------------------------------------------------------------------------
__global__ __launch_bounds__(256) void step_kernel(
        const unsigned short* __restrict__ Wf,
        const unsigned short* __restrict__ hbf_in,
        unsigned short* __restrict__ hbf_out,
        const float* __restrict__ vel_t,
        const float* __restrict__ hprev,
        float* __restrict__ acts_t,
        float* __restrict__ outT) {
    const int lane = threadIdx.x & 63;
    const int w    = threadIdx.x >> 6;
    const int bid  = blockIdx.x;
    const int mg   = bid >> 7;
    const int n    = bid & 127;
    const int base_b = mg * 64 + w * 16;
    const int base_j = n * 16;
    const int r16  = lane & 15;
    const int q4   = lane >> 4;

    const int j = base_j + r16;
    const bf16x8* Ap = reinterpret_cast<const bf16x8*>(
        hbf_in + (size_t)(base_b + r16) * H_DIM + q4 * 8);
    const unsigned short* wslot = Wf + (size_t)(j >> 6) * 131072 + (size_t)(j & 63) * 8;

    f32x4 acc0 = {0.f, 0.f, 0.f, 0.f};
    f32x4 acc1 = {0.f, 0.f, 0.f, 0.f};
    #pragma unroll 8
    for (int kk = 0; kk < 32; ++kk) {
        bf16x8 a0 = Ap[kk * 4];
        bf16x8 a1 = Ap[kk * 4 + 128];
        bf16x8 b0 = *reinterpret_cast<const bf16x8*>(wslot + (size_t)(kk * 4 + q4) * 512);
        bf16x8 b1 = *reinterpret_cast<const bf16x8*>(wslot + (size_t)((kk + 32) * 4 + q4) * 512);
        acc0 = __builtin_amdgcn_mfma_f32_16x16x32_bf16(a0, b0, acc0, 0, 0, 0);
        acc1 = __builtin_amdgcn_mfma_f32_16x16x32_bf16(a1, b1, acc1, 0, 0, 0);
    }
    f32x4 h2h = acc0 + acc1;

    const float gamma = (j < N_HALF) ? -1.0f : 1.0f;
    const int brow0 = base_b + q4 * 4;
    #pragma unroll
    for (int i = 0; i < 4; ++i) {
        const int b = brow0 + i;
        const float v  = vel_t[b];
        const float hp = hprev[(size_t)b * H_DIM + j];
        const float pre = fmaf(v, gamma, 1.0f) + h2h[i];
        const float hn = OMA_F * hp + ALPHA_F * fmaxf(pre, 0.0f);
        acts_t[(size_t)b * H_DIM + j] = hn;
        hbf_out[(size_t)b * H_DIM + j] = f2bf(hn);
        if (outT) outT[(size_t)b * H_DIM + j] = hn;
    }
}

// ---------------------------------------------------------------------------
extern "C" void kernel_launch(void* const* d_in, const int* in_sizes, int n_in,
                              void* d_out, int out_size, void* d_ws, size_t ws_size,
                              hipStream_t stream) {
    const float* x       = (const float*)d_in[0];  // [T,B,IN]
    const float* hidden0 = (const float*)d_in[1];  // [B,H]
    const float* w_attr  = (const float*)d_in[2];  // [H,H]
    const float* w_in    = (const float*)d_in[3];  // [1,IN]

    float* acts = (float*)d_out;                               // [T,B,H]
    float* outT = acts + (size_t)T_STEPS * B_SZ * H_DIM;       // [B,H]

    unsigned char* ws = (unsigned char*)d_ws;
    unsigned short* Wf   = (unsigned short*)ws;                             // 8 MB
    unsigned short* hbf0 = (unsigned short*)(ws + ((size_t)8 << 20));       // 512 KB
    unsigned short* hbf1 = hbf0 + (size_t)B_SZ * H_DIM;                     // 512 KB
    float* vel = (float*)(ws + ((size_t)8 << 20) + (size_t)2 * B_SZ * H_DIM * 2); // 256 KB
    unsigned* flags = (unsigned*)(ws + ((size_t)8 << 20) + ((size_t)1 << 20) + (256 << 10)); // 4 KB

    hipMemsetAsync(flags, 0, 4096, stream);
    wf_kernel<<<dim3(32, 32), dim3(64, 4), 0, stream>>>(w_attr, Wf);
    vel_kernel<<<(T_STEPS * B_SZ + 255) / 256, 256, 0, stream>>>(x, w_in, vel);
    hbf_init_kernel<<<(B_SZ * H_DIM + 255) / 256, 256, 0, stream>>>(hidden0, hbf0);

    void* args[] = {(void*)&Wf, (void*)&hbf0, (void*)&hbf1, (void*)&vel,
                    (void*)&hidden0, (void*)&acts, (void*)&outT, (void*)&flags};
    hipError_t rc = hipLaunchCooperativeKernel(
        reinterpret_cast<void*>(ring_coop_kernel),
        dim3(256), dim3(512), args, 0, stream);

    if (rc != hipSuccess) {
        // fallback: per-step launches
        for (int t = 0; t < T_STEPS; ++t) {
            const unsigned short* hin = (t & 1) ? hbf1 : hbf0;
            unsigned short* hout      = (t & 1) ? hbf0 : hbf1;
            const float* hprev = (t == 0) ? hidden0 : acts + (size_t)(t - 1) * B_SZ * H_DIM;
            step_kernel<<<256, 256, 0, stream>>>(
                Wf, hin, hout, vel + (size_t)t * B_SZ, hprev,
                acts + (size_t)t * B_SZ * H_DIM,
                (t == T_STEPS - 1) ? outT : nullptr);
        }
    }
}

// Round 16
// 1876.673 us; speedup vs baseline: 1.4434x; 1.0443x over previous
//
#include <hip/hip_runtime.h>

#define H_DIM   2048
#define N_HALF  1024
#define B_SZ    128
#define T_STEPS 512
#define IN_DIM  64
#define ALPHA_F 0.05f
#define OMA_F   0.95f   // 1 - ALPHA

typedef __bf16 bf16x8 __attribute__((ext_vector_type(8)));
typedef float  f32x4  __attribute__((ext_vector_type(4)));
typedef unsigned int u32x4 __attribute__((ext_vector_type(4)));

// round-to-nearest-even f32 -> bf16 bits
__device__ __forceinline__ unsigned short f2bf(float f) {
    union { float f; unsigned int u; } v; v.f = f;
    unsigned int u = v.u;
    u += 0x7FFFu + ((u >> 16) & 1u);
    return (unsigned short)(u >> 16);
}

// ---------------------------------------------------------------------------
// Wf: weights in MFMA-fragment order:
//   Wf[(j>>6)*131072 + ((ks*4 + q4)*64 + (j&63))*8 + e] = bf16(W[k][j])
//   with ks = k>>5, q4 = (k>>3)&3, e = k&7.
// ---------------------------------------------------------------------------
__global__ void wf_kernel(const float* __restrict__ W, unsigned short* __restrict__ Wf) {
    __shared__ float tile[64][65];     // tile[kk][jj] = W[kb+kk][jb+jj]
    const int jb = blockIdx.x * 64;
    const int kb = blockIdx.y * 64;
    const int t  = threadIdx.y * 64 + threadIdx.x;   // 0..255
    const int tx = threadIdx.x, ty = threadIdx.y;
    #pragma unroll
    for (int r = ty; r < 64; r += 4)
        tile[r][tx] = W[(size_t)(kb + r) * H_DIM + jb + tx];
    __syncthreads();
    #pragma unroll
    for (int cc = 0; cc < 2; ++cc) {
        const int c  = t * 2 + cc;        // 0..511
        const int jj = c >> 3;            // 0..63
        const int kc = c & 7;             // 8-K group within tile
        const int j  = jb + jj;
        const int k0 = kb + kc * 8;
        unsigned short v[8];
        #pragma unroll
        for (int e = 0; e < 8; ++e)
            v[e] = f2bf(tile[kc * 8 + e][jj]);
        const int ks = k0 >> 5;
        const int q4 = (k0 >> 3) & 3;
        const size_t dst = (size_t)(j >> 6) * 131072 +
                           ((size_t)(ks * 4 + q4) * 64 + (j & 63)) * 8;
        *reinterpret_cast<u32x4*>(Wf + dst) = *reinterpret_cast<u32x4*>(v);
    }
}

// ---------------------------------------------------------------------------
__global__ void vel_kernel(const float* __restrict__ x, const float* __restrict__ w_in,
                           float* __restrict__ vel) {
    const int tb = blockIdx.x * blockDim.x + threadIdx.x;
    if (tb >= T_STEPS * B_SZ) return;
    const float* xp = x + (size_t)tb * IN_DIM;
    float s = 0.f;
    #pragma unroll
    for (int i = 0; i < IN_DIM; i += 4) {
        float4 xv = *reinterpret_cast<const float4*>(xp + i);
        float4 wv = *reinterpret_cast<const float4*>(w_in + i);
        s += xv.x * wv.x + xv.y * wv.y + xv.z * wv.z + xv.w * wv.w;
    }
    vel[tb] = s;
}

// ---------------------------------------------------------------------------
__global__ void hbf_init_kernel(const float* __restrict__ h0, unsigned short* __restrict__ hbf) {
    const int i = blockIdx.x * blockDim.x + threadIdx.x;
    hbf[i] = f2bf(h0[i]);
}

// ---------------------------------------------------------------------------
// Persistent kernel: 256 blocks (1/CU) x 512 threads (8 waves).
// Block tile 16 rows x 64 cols; 8 waves = 4 col-quarters x 2 K-halves.
// r13/r15 protocol (best: 1960us): B in registers (Breg[32], W constant);
// h handoff sc0+sc1 both sides (the ONLY data needing L3 coherence);
// immutable (Wf, vel) cached; ZERO cache-maintenance ops. h_prev in regs.
// Staging: ONE wave-parallel poll of the wave's 4 producer flags, then
// 8x16B sc0 sc1 loads all in flight; LDS chunk swizzle row^kcl.
// r16: acts is write-only -> plain CACHED stores direct from the epilogue
// (L2 write-back = hardware store buffer; drains in background; nothing
// else lives in L2). hT tail likewise direct from hreg. The post-hbuf
// store phase is now only the 128 h-threads (bypass + drain before flag).
// ---------------------------------------------------------------------------
__global__ __launch_bounds__(512, 1) void ring_coop_kernel(
        const unsigned short* __restrict__ Wf,
        unsigned short* __restrict__ hbf0,
        unsigned short* __restrict__ hbf1,
        const float* __restrict__ vel,
        const float* __restrict__ hidden0,
        float* __restrict__ acts,
        float* __restrict__ outT,
        unsigned* __restrict__ flags) {
    __shared__ __align__(16) unsigned char A_lds[65536];   // swizzled frag chunks
    __shared__ __align__(16) f32x4 pacc[256];              // [colq][lane]
    __shared__ __align__(16) float hbuf[16][64];           // h-pack transpose

    const int tid = threadIdx.x;
    const int bid = blockIdx.x;
    // XCD swizzle (bid%8 = XCD): XCD x owns colgs {4x..4x+3} for ALL rowgs.
    const int colg = (bid & 7) * 4 + ((bid >> 3) & 3);   // 0..31 (64-col groups)
    const int rowg = bid >> 5;                            // 0..7  (16-row groups)
    const int colbase = colg * 64;
    const int rowbase = rowg * 16;

    const int lane = tid & 63, w = tid >> 6;   // 8 waves
    const int colq = w & 3, khalf = w >> 2;
    const int r16 = lane & 15, q4 = lane >> 4;
    const int j = colbase + colq * 16 + r16;
    const float gamma = (j < N_HALF) ? -1.0f : 1.0f;

    // staging lane identity: rows srow / srow+8, K-subchunk kcl (8 K each)
    const int srow = lane >> 3;      // 0..7
    const int kcl  = lane & 7;       // 0..7

    unsigned* rflags = flags + rowg * 128;    // flag for cg at rflags[cg*4]

    // ---- one-time: B fragments into registers (W constant across steps) ----
    const unsigned short* bgbase = Wf + (size_t)colg * 131072
                                   + (size_t)(khalf * 128 + q4) * 512
                                   + (size_t)(colq * 16 + r16) * 8;
    bf16x8 Breg[32];
    #pragma unroll
    for (int s = 0; s < 32; ++s)
        Breg[s] = *reinterpret_cast<const bf16x8*>(bgbase + (size_t)s * 2048);

    // h_prev registers (khalf==0 waves): rows rowbase+q4*4+i, col j
    f32x4 hreg = {0.f, 0.f, 0.f, 0.f};
    if (khalf == 0) {
        #pragma unroll
        for (int i = 0; i < 4; ++i)
            hreg[i] = hidden0[(size_t)(rowbase + q4 * 4 + i) * H_DIM + j];
    }

    const int xe = r16 ^ q4;     // read swizzle, even s
    const int xo = xe ^ 4;       // read swizzle, odd  s

    // this wave's 4 staged chunks: cg0 + {0,8,16,24} (mod 32)
    const int cg0 = (colg + 1 + w) & 31;
    const int cgA = cg0, cgB = (cg0 + 8) & 31, cgC = (cg0 + 16) & 31, cgD = (cg0 + 24) & 31;
    // flag index this lane polls (lanes 0..3)
    const int pollcg = (cg0 + 8 * (lane & 3)) & 31;

    for (int t = 0; t < T_STEPS; ++t) {
        const unsigned short* hin  = (t & 1) ? hbf1 : hbf0;
        unsigned short*       hout = (t & 1) ? hbf0 : hbf1;
        const float* vel_t = vel + (size_t)t * B_SZ;
        float* acts_t = acts + (size_t)t * B_SZ * H_DIM;

        // vel preload (cached, immutable) — issue before the poll
        f32x4 vel4 = {0.f, 0.f, 0.f, 0.f};
        if (khalf == 0)
            vel4 = *reinterpret_cast<const f32x4*>(vel_t + rowbase + q4 * 4);

        // ---- ONE wave-parallel poll of this wave's 4 producer flags ----
        for (;;) {
            int ok = 1;
            if (lane < 4) {
                unsigned v = __hip_atomic_load(rflags + pollcg * 4,
                                 __ATOMIC_RELAXED, __HIP_MEMORY_SCOPE_AGENT);
                ok = (v >= (unsigned)t);
            }
            if (__all(ok)) break;
            __builtin_amdgcn_s_sleep(1);
        }
        asm volatile("" ::: "memory");   // loads below can't hoist above poll

        // ---- stage 4 chunks: 8 x 16B sc0 sc1 loads, all in flight ----
        {
            const unsigned short* base = hin + (size_t)(rowbase + srow) * H_DIM + kcl * 8;
            u32x4 a0, a1, b0, b1, c0, c1, d0, d1;
            const unsigned short* pA = base + cgA * 64;
            const unsigned short* pB = base + cgB * 64;
            const unsigned short* pC = base + cgC * 64;
            const unsigned short* pD = base + cgD * 64;
            asm volatile("global_load_dwordx4 %0, %1, off sc0 sc1" : "=v"(a0) : "v"(pA));
            asm volatile("global_load_dwordx4 %0, %1, off sc0 sc1" : "=v"(a1) : "v"(pA + 8 * H_DIM));
            asm volatile("global_load_dwordx4 %0, %1, off sc0 sc1" : "=v"(b0) : "v"(pB));
            asm volatile("global_load_dwordx4 %0, %1, off sc0 sc1" : "=v"(b1) : "v"(pB + 8 * H_DIM));
            asm volatile("global_load_dwordx4 %0, %1, off sc0 sc1" : "=v"(c0) : "v"(pC));
            asm volatile("global_load_dwordx4 %0, %1, off sc0 sc1" : "=v"(c1) : "v"(pC + 8 * H_DIM));
            asm volatile("global_load_dwordx4 %0, %1, off sc0 sc1" : "=v"(d0) : "v"(pD));
            asm volatile("global_load_dwordx4 %0, %1, off sc0 sc1" : "=v"(d1) : "v"(pD + 8 * H_DIM));
            asm volatile("s_waitcnt vmcnt(0)" ::: "memory");
            __builtin_amdgcn_sched_barrier(0);
            const int lo_sw = srow ^ kcl, hi_sw = (srow + 8) ^ kcl;
            *reinterpret_cast<u32x4*>(A_lds + (size_t)((cgA * 8 + kcl) * 16 + lo_sw) * 16) = a0;
            *reinterpret_cast<u32x4*>(A_lds + (size_t)((cgA * 8 + kcl) * 16 + hi_sw) * 16) = a1;
            *reinterpret_cast<u32x4*>(A_lds + (size_t)((cgB * 8 + kcl) * 16 + lo_sw) * 16) = b0;
            *reinterpret_cast<u32x4*>(A_lds + (size_t)((cgB * 8 + kcl) * 16 + hi_sw) * 16) = b1;
            *reinterpret_cast<u32x4*>(A_lds + (size_t)((cgC * 8 + kcl) * 16 + lo_sw) * 16) = c0;
            *reinterpret_cast<u32x4*>(A_lds + (size_t)((cgC * 8 + kcl) * 16 + hi_sw) * 16) = c1;
            *reinterpret_cast<u32x4*>(A_lds + (size_t)((cgD * 8 + kcl) * 16 + lo_sw) * 16) = d0;
            *reinterpret_cast<u32x4*>(A_lds + (size_t)((cgD * 8 + kcl) * 16 + hi_sw) * 16) = d1;
        }
        __syncthreads();

        // ---- GEMM: 32 MFMAs/wave, A from swizzled LDS, B from REGISTERS ----
        const unsigned char* Abase = A_lds + (size_t)(khalf * 2048 + q4 * 16) * 16;
        f32x4 acc0 = {0.f,0.f,0.f,0.f}, acc1 = {0.f,0.f,0.f,0.f};
        f32x4 acc2 = {0.f,0.f,0.f,0.f}, acc3 = {0.f,0.f,0.f,0.f};
        #pragma unroll
        for (int s = 0; s < 32; s += 4) {
            bf16x8 a0 = *reinterpret_cast<const bf16x8*>(Abase +
                (size_t)((s + 0) * 64 + xe) * 16);
            bf16x8 a1 = *reinterpret_cast<const bf16x8*>(Abase +
                (size_t)((s + 1) * 64 + xo) * 16);
            bf16x8 a2 = *reinterpret_cast<const bf16x8*>(Abase +
                (size_t)((s + 2) * 64 + xe) * 16);
            bf16x8 a3 = *reinterpret_cast<const bf16x8*>(Abase +
                (size_t)((s + 3) * 64 + xo) * 16);
            acc0 = __builtin_amdgcn_mfma_f32_16x16x32_bf16(a0, Breg[s + 0], acc0, 0, 0, 0);
            acc1 = __builtin_amdgcn_mfma_f32_16x16x32_bf16(a1, Breg[s + 1], acc1, 0, 0, 0);
            acc2 = __builtin_amdgcn_mfma_f32_16x16x32_bf16(a2, Breg[s + 2], acc2, 0, 0, 0);
            acc3 = __builtin_amdgcn_mfma_f32_16x16x32_bf16(a3, Breg[s + 3], acc3, 0, 0, 0);
        }
        f32x4 psum = (acc0 + acc1) + (acc2 + acc3);

        // ---- K-pair reduce + epilogue ----
        if (khalf == 1) pacc[colq * 64 + lane] = psum;
        __syncthreads();
        if (khalf == 0) {
            const f32x4 h2h = psum + pacc[colq * 64 + lane];
            #pragma unroll
            for (int i = 0; i < 4; ++i) {
                const int row = rowbase + q4 * 4 + i;
                const float pre = fmaf(vel4[i], gamma, 1.0f) + h2h[i];
                const float hn = OMA_F * hreg[i] + ALPHA_F * fmaxf(pre, 0.0f);
                hreg[i] = hn;
                hbuf[q4 * 4 + i][colq * 16 + r16] = hn;          // for h-pack
                acts_t[(size_t)row * H_DIM + j] = hn;            // plain cached
                if (t == T_STEPS - 1)
                    outT[(size_t)row * H_DIM + j] = hn;          // plain cached
            }
        }
        __syncthreads();

        // ---- h bf16 bypass stores (the only stores on the handoff path) ----
        if (tid >= 256 && tid < 384) {
            const int t2 = tid - 256;
            const int row2 = t2 >> 3, c8 = (t2 & 7) * 8;
            unsigned pk[4];
            #pragma unroll
            for (int e = 0; e < 4; ++e)
                pk[e] = (unsigned)f2bf(hbuf[row2][c8 + 2 * e]) |
                        ((unsigned)f2bf(hbuf[row2][c8 + 2 * e + 1]) << 16);
            u32x4 hv = {pk[0], pk[1], pk[2], pk[3]};
            unsigned short* dst = hout + (size_t)(rowbase + row2) * H_DIM + colbase + c8;
            asm volatile("global_store_dwordx4 %0, %1, off sc0 sc1"
                         :: "v"(dst), "v"(hv) : "memory");
            asm volatile("s_waitcnt vmcnt(0)" ::: "memory");
        }
        __syncthreads();                 // h stores drained block-wide
        if (tid == 0 && t < T_STEPS - 1)
            __hip_atomic_store(rflags + colg * 4, (unsigned)(t + 1),
                               __ATOMIC_RELAXED, __HIP_MEMORY_SCOPE_AGENT);
    }
}

// ---------------------------------------------------------------------------
// Fallback per-step kernel (Wf layout) if cooperative launch fails.
// ---------------------------------------------------------------------------
__global__ __launch_bounds__(256) void step_kernel(
        const unsigned short* __restrict__ Wf,
        const unsigned short* __restrict__ hbf_in,
        unsigned short* __restrict__ hbf_out,
        const float* __restrict__ vel_t,
        const float* __restrict__ hprev,
        float* __restrict__ acts_t,
        float* __restrict__ outT) {
    const int lane = threadIdx.x & 63;
    const int w    = threadIdx.x >> 6;
    const int bid  = blockIdx.x;
    const int mg   = bid >> 7;
    const int n    = bid & 127;
    const int base_b = mg * 64 + w * 16;
    const int base_j = n * 16;
    const int r16  = lane & 15;
    const int q4   = lane >> 4;

    const int j = base_j + r16;
    const bf16x8* Ap = reinterpret_cast<const bf16x8*>(
        hbf_in + (size_t)(base_b + r16) * H_DIM + q4 * 8);
    const unsigned short* wslot = Wf + (size_t)(j >> 6) * 131072 + (size_t)(j & 63) * 8;

    f32x4 acc0 = {0.f, 0.f, 0.f, 0.f};
    f32x4 acc1 = {0.f, 0.f, 0.f, 0.f};
    #pragma unroll 8
    for (int kk = 0; kk < 32; ++kk) {
        bf16x8 a0 = Ap[kk * 4];
        bf16x8 a1 = Ap[kk * 4 + 128];
        bf16x8 b0 = *reinterpret_cast<const bf16x8*>(wslot + (size_t)(kk * 4 + q4) * 512);
        bf16x8 b1 = *reinterpret_cast<const bf16x8*>(wslot + (size_t)((kk + 32) * 4 + q4) * 512);
        acc0 = __builtin_amdgcn_mfma_f32_16x16x32_bf16(a0, b0, acc0, 0, 0, 0);
        acc1 = __builtin_amdgcn_mfma_f32_16x16x32_bf16(a1, b1, acc1, 0, 0, 0);
    }
    f32x4 h2h = acc0 + acc1;

    const float gamma = (j < N_HALF) ? -1.0f : 1.0f;
    const int brow0 = base_b + q4 * 4;
    #pragma unroll
    for (int i = 0; i < 4; ++i) {
        const int b = brow0 + i;
        const float v  = vel_t[b];
        const float hp = hprev[(size_t)b * H_DIM + j];
        const float pre = fmaf(v, gamma, 1.0f) + h2h[i];
        const float hn = OMA_F * hp + ALPHA_F * fmaxf(pre, 0.0f);
        acts_t[(size_t)b * H_DIM + j] = hn;
        hbf_out[(size_t)b * H_DIM + j] = f2bf(hn);
        if (outT) outT[(size_t)b * H_DIM + j] = hn;
    }
}

// ---------------------------------------------------------------------------
extern "C" void kernel_launch(void* const* d_in, const int* in_sizes, int n_in,
                              void* d_out, int out_size, void* d_ws, size_t ws_size,
                              hipStream_t stream) {
    const float* x       = (const float*)d_in[0];  // [T,B,IN]
    const float* hidden0 = (const float*)d_in[1];  // [B,H]
    const float* w_attr  = (const float*)d_in[2];  // [H,H]
    const float* w_in    = (const float*)d_in[3];  // [1,IN]

    float* acts = (float*)d_out;                               // [T,B,H]
    float* outT = acts + (size_t)T_STEPS * B_SZ * H_DIM;       // [B,H]

    unsigned char* ws = (unsigned char*)d_ws;
    unsigned short* Wf   = (unsigned short*)ws;                             // 8 MB
    unsigned short* hbf0 = (unsigned short*)(ws + ((size_t)8 << 20));       // 512 KB
    unsigned short* hbf1 = hbf0 + (size_t)B_SZ * H_DIM;                     // 512 KB
    float* vel = (float*)(ws + ((size_t)8 << 20) + (size_t)2 * B_SZ * H_DIM * 2); // 256 KB
    unsigned* flags = (unsigned*)(ws + ((size_t)8 << 20) + ((size_t)1 << 20) + (256 << 10)); // 4 KB

    hipMemsetAsync(flags, 0, 4096, stream);
    wf_kernel<<<dim3(32, 32), dim3(64, 4), 0, stream>>>(w_attr, Wf);
    vel_kernel<<<(T_STEPS * B_SZ + 255) / 256, 256, 0, stream>>>(x, w_in, vel);
    hbf_init_kernel<<<(B_SZ * H_DIM + 255) / 256, 256, 0, stream>>>(hidden0, hbf0);

    void* args[] = {(void*)&Wf, (void*)&hbf0, (void*)&hbf1, (void*)&vel,
                    (void*)&hidden0, (void*)&acts, (void*)&outT, (void*)&flags};
    hipError_t rc = hipLaunchCooperativeKernel(
        reinterpret_cast<void*>(ring_coop_kernel),
        dim3(256), dim3(512), args, 0, stream);

    if (rc != hipSuccess) {
        // fallback: per-step launches
        for (int t = 0; t < T_STEPS; ++t) {
            const unsigned short* hin = (t & 1) ? hbf1 : hbf0;
            unsigned short* hout      = (t & 1) ? hbf0 : hbf1;
            const float* hprev = (t == 0) ? hidden0 : acts + (size_t)(t - 1) * B_SZ * H_DIM;
            step_kernel<<<256, 256, 0, stream>>>(
                Wf, hin, hout, vel + (size_t)t * B_SZ, hprev,
                acts + (size_t)t * B_SZ * H_DIM,
                (t == T_STEPS - 1) ? outT : nullptr);
        }
    }
}